// Round 3
// baseline (171.568 us; speedup 1.0000x reference)
//
#include <hip/hip_runtime.h>

#define NSPK 256
#define MUTT 64
#define DDIM 1024
#define NROW (NSPK * MUTT)   // 16384

using frag_ab = __attribute__((ext_vector_type(8))) short;   // 8 bf16 (4 VGPRs)
using frag_cd = __attribute__((ext_vector_type(4))) float;   // 4 fp32 acc

static __device__ __forceinline__ unsigned short f32_to_bf16(float f) {
    unsigned int u = __float_as_uint(f);
    return (unsigned short)((u + 0x7FFFu + ((u >> 16) & 1u)) >> 16);   // RNE
}
static __device__ __forceinline__ unsigned int pack2(float a, float b) {
    return (unsigned)f32_to_bf16(a) | ((unsigned)f32_to_bf16(b) << 16);
}

// ======================= FAST PATH =======================

// k_prep v2: wave-per-row. Block = 16 rows of one speaker; wave w owns rows 4w..4w+3.
// Produces: Sp partial sums (P=4), bf16 cast ebf, per-row q=||e||^2.
__global__ void __launch_bounds__(256) k_prep(const float* __restrict__ emb,
                                              float* __restrict__ Sp,
                                              unsigned short* __restrict__ ebf,
                                              float* __restrict__ qg) {
    const int j = blockIdx.x;
    const int h = blockIdx.y;
    const int t = threadIdx.x;
    const int lane = t & 63, wave = t >> 6;
    const size_t rowbase = (size_t)j * MUTT + (size_t)h * 16;
    __shared__ float sacc[4][DDIM];    // 16 KB
    __shared__ float qsh[16];

    float4 s[4];
    #pragma unroll
    for (int c = 0; c < 4; ++c) s[c] = make_float4(0.f, 0.f, 0.f, 0.f);

    #pragma unroll
    for (int r = 0; r < 4; ++r) {
        const int row = wave * 4 + r;                     // 0..15
        const float* src = emb + (rowbase + row) * DDIM;
        unsigned short* dst = ebf + (rowbase + row) * DDIM;
        float4 v[4];
        #pragma unroll
        for (int c = 0; c < 4; ++c)
            v[c] = *(const float4*)(src + c * 256 + lane * 4);
        float q = 0.f;
        #pragma unroll
        for (int c = 0; c < 4; ++c) {
            s[c].x += v[c].x; s[c].y += v[c].y; s[c].z += v[c].z; s[c].w += v[c].w;
            q += v[c].x * v[c].x + v[c].y * v[c].y + v[c].z * v[c].z + v[c].w * v[c].w;
            *(uint2*)(dst + c * 256 + lane * 4) =
                make_uint2(pack2(v[c].x, v[c].y), pack2(v[c].z, v[c].w));
        }
        #pragma unroll
        for (int off = 32; off > 0; off >>= 1) q += __shfl_down(q, off, 64);
        if (lane == 0) qsh[row] = q;
    }
    #pragma unroll
    for (int c = 0; c < 4; ++c)
        *(float4*)&sacc[wave][c * 256 + lane * 4] = s[c];
    __syncthreads();
    if (t < 16) qg[rowbase + t] = qsh[t];
    float4 a0 = *(float4*)&sacc[0][t * 4];
    float4 a1 = *(float4*)&sacc[1][t * 4];
    float4 a2 = *(float4*)&sacc[2][t * 4];
    float4 a3 = *(float4*)&sacc[3][t * 4];
    float4 r = make_float4(a0.x + a1.x + a2.x + a3.x, a0.y + a1.y + a2.y + a3.y,
                           a0.z + a1.z + a2.z + a3.z, a0.w + a1.w + a2.w + a3.w);
    *(float4*)(Sp + ((size_t)h * NSPK + j) * DDIM + (size_t)t * 4) = r;
}

// k_center<P>: sum P partials, write bf16 centers + ||S||^2, ||S||.
template <int P>
__global__ void k_center(const float* __restrict__ Sp, unsigned short* __restrict__ cbf,
                         float* __restrict__ normS2g, float* __restrict__ normSg) {
    const int j = blockIdx.x;
    const int t = threadIdx.x;
    float4 v = make_float4(0.f, 0.f, 0.f, 0.f);
    #pragma unroll
    for (int p = 0; p < P; ++p) {
        float4 a = *(const float4*)(Sp + ((size_t)p * NSPK + j) * DDIM + (size_t)t * 4);
        v.x += a.x; v.y += a.y; v.z += a.z; v.w += a.w;
    }
    float sq = v.x * v.x + v.y * v.y + v.z * v.z + v.w * v.w;
    #pragma unroll
    for (int off = 32; off > 0; off >>= 1) sq += __shfl_down(sq, off, 64);
    __shared__ float ws[4];
    __shared__ float sc_sh;
    const int lane = t & 63, wave = t >> 6;
    if (lane == 0) ws[wave] = sq;
    __syncthreads();
    if (t == 0) {
        float tot = ws[0] + ws[1] + ws[2] + ws[3];
        normS2g[j] = tot;
        normSg[j]  = sqrtf(tot);
        float msq = tot * (1.0f / 4096.0f);
        sc_sh = rsqrtf(fmaxf(msq, 1e-12f)) * (1.0f / 64.0f);
    }
    __syncthreads();
    const float sc = sc_sh;
    *(uint2*)(cbf + (size_t)j * DDIM + (size_t)t * 4) =
        make_uint2(pack2(v.x * sc, v.y * sc), pack2(v.z * sc, v.w * sc));
}

// k_gemm3: 64x128 tile, BK=64, SINGLE 24 KB LDS buffer + register prefetch.
// Tile k+1 is loaded to VGPRs before tile k's MFMAs; vmcnt wait only hits at the
// post-barrier ds_write. XOR swizzle (chunk ^= row&7) keeps b128 LDS ops conflict-free.
#define RT 64
#define CT 128
#define BK 64
__global__ void __launch_bounds__(256, 4)
k_gemm3(const unsigned short* __restrict__ ebf, const unsigned short* __restrict__ cbf,
        const float* __restrict__ qg, const float* __restrict__ n2g,
        const float* __restrict__ n1g,
        const float* __restrict__ wp, const float* __restrict__ bp,
        float* __restrict__ out) {
    __shared__ unsigned short lds[RT * BK + CT * BK];   // 24 KB

    const int tid = threadIdx.x, lane = tid & 63, wave = tid >> 6;
    const int rt = blockIdx.x;            // row tile == speaker
    const int ct = blockIdx.y;            // col half
    const int row0 = rt * RT;
    const int c0 = ct * CT;
    const int jspk = rt;

    // staging: chunk c = 16 B; LDS linear chunk (row,sw) holds G[row][sw^(row&7)]
    int aoff[2], boff[4];
    #pragma unroll
    for (int i = 0; i < 2; ++i) {
        int ca = i * 256 + tid, row = ca >> 3, sw = ca & 7;
        aoff[i] = row * (DDIM * 2) + ((sw ^ (row & 7)) << 4);
    }
    #pragma unroll
    for (int i = 0; i < 4; ++i) {
        int cb = i * 256 + tid, row = cb >> 3, sw = cb & 7;
        boff[i] = row * (DDIM * 2) + ((sw ^ (row & 7)) << 4);
    }
    const char* agbase = (const char*)(ebf + (size_t)row0 * DDIM);
    const char* bgbase = (const char*)(cbf + (size_t)c0 * DDIM);

    const int quad = lane >> 4;
    const int m16 = lane & 15;
    const int wrow = wave >> 1, wcol = wave & 1;
    int arow[2], brow[4];
    arow[0] = wrow * 32 + m16; arow[1] = arow[0] + 16;
    #pragma unroll
    for (int cc = 0; cc < 4; ++cc) brow[cc] = wcol * 64 + cc * 16 + m16;

    frag_cd acc[2][4];
    #pragma unroll
    for (int rr = 0; rr < 2; ++rr)
        #pragma unroll
        for (int cc = 0; cc < 4; ++cc) acc[rr][cc] = (frag_cd){0.f, 0.f, 0.f, 0.f};

    uint4 pa[2], pb[4];
    // prologue: tile 0 -> regs -> LDS
    #pragma unroll
    for (int i = 0; i < 2; ++i) pa[i] = *(const uint4*)(agbase + aoff[i]);
    #pragma unroll
    for (int i = 0; i < 4; ++i) pb[i] = *(const uint4*)(bgbase + boff[i]);
    #pragma unroll
    for (int i = 0; i < 2; ++i) *(uint4*)&lds[(i * 256 + tid) * 8] = pa[i];
    #pragma unroll
    for (int i = 0; i < 4; ++i) *(uint4*)&lds[RT * BK + (i * 256 + tid) * 8] = pb[i];
    __syncthreads();

    const int NIT = DDIM / BK;   // 16
    for (int it = 0; it < NIT; ++it) {
        // issue next-tile global loads FIRST (latency overlapped with MFMAs below)
        if (it + 1 < NIT) {
            const char* ag = agbase + (size_t)(it + 1) * BK * 2;
            const char* bg = bgbase + (size_t)(it + 1) * BK * 2;
            #pragma unroll
            for (int i = 0; i < 2; ++i) pa[i] = *(const uint4*)(ag + aoff[i]);
            #pragma unroll
            for (int i = 0; i < 4; ++i) pb[i] = *(const uint4*)(bg + boff[i]);
        }
        #pragma unroll
        for (int s = 0; s < 2; ++s) {
            frag_ab af[2], bf[4];
            const int kc = (s << 2) + quad;
            #pragma unroll
            for (int rr = 0; rr < 2; ++rr) {
                int addr = arow[rr] * 128 + ((kc ^ (arow[rr] & 7)) << 4);
                af[rr] = *(const frag_ab*)&lds[addr >> 1];
            }
            #pragma unroll
            for (int cc = 0; cc < 4; ++cc) {
                int addr = (RT * BK * 2) + brow[cc] * 128 + ((kc ^ (brow[cc] & 7)) << 4);
                bf[cc] = *(const frag_ab*)&lds[addr >> 1];
            }
            #pragma unroll
            for (int rr = 0; rr < 2; ++rr)
                #pragma unroll
                for (int cc = 0; cc < 4; ++cc)
                    acc[rr][cc] = __builtin_amdgcn_mfma_f32_16x16x32_bf16(
                        af[rr], bf[cc], acc[rr][cc], 0, 0, 0);
        }
        __syncthreads();               // all waves done reading LDS
        if (it + 1 < NIT) {
            #pragma unroll
            for (int i = 0; i < 2; ++i) *(uint4*)&lds[(i * 256 + tid) * 8] = pa[i];
            #pragma unroll
            for (int i = 0; i < 4; ++i) *(uint4*)&lds[RT * BK + (i * 256 + tid) * 8] = pb[i];
            __syncthreads();           // LDS ready for next iter
        }
    }

    const float wv = wp[0], bv = bp[0];
    const float ns2 = n2g[jspk], ns = n1g[jspk];
    #pragma unroll
    for (int rr = 0; rr < 2; ++rr) {
        int rbase = wrow * 32 + rr * 16 + (quad << 2);
        #pragma unroll
        for (int cc = 0; cc < 4; ++cc) {
            int col = c0 + wcol * 64 + cc * 16 + m16;
            frag_cd v = acc[rr][cc];
            #pragma unroll
            for (int r2 = 0; r2 < 4; ++r2) {
                int grow = row0 + rbase + r2;
                float val = v[r2];
                if (col == jspk) {
                    float q = qg[grow];
                    float rd = val * ns;
                    float den2 = ns2 - 2.f * rd + q;
                    val = (rd - q) * rsqrtf(fmaxf(den2, 1e-12f));
                }
                out[(size_t)grow * NSPK + col] = wv * val + bv;
            }
        }
    }
}

// ======================= FALLBACK (small ws) =======================

__global__ void k_sums(const float* __restrict__ emb, float* __restrict__ Sp) {
    const int j = blockIdx.x;
    const int h = blockIdx.y;
    const int c = threadIdx.x;
    const float* base = emb + ((size_t)j * MUTT + (size_t)h * 32) * DDIM + (size_t)c * 4;
    float4 acc = make_float4(0.f, 0.f, 0.f, 0.f);
    #pragma unroll 8
    for (int m = 0; m < 32; ++m) {
        float4 v = *(const float4*)(base + (size_t)m * DDIM);
        acc.x += v.x; acc.y += v.y; acc.z += v.z; acc.w += v.w;
    }
    *(float4*)(Sp + ((size_t)h * NSPK + j) * DDIM + (size_t)c * 4) = acc;
}

__global__ void __launch_bounds__(256)
k_gemm_old(const float* __restrict__ emb, const unsigned short* __restrict__ cbf,
           const float* __restrict__ normS2g, const float* __restrict__ normSg,
           const float* __restrict__ wp, const float* __restrict__ bp,
           float* __restrict__ out) {
    __shared__ unsigned short Asm[32][32];
    __shared__ unsigned short Bsm[256][32];
    __shared__ float qpart[32][8];
    __shared__ float qfin[32];
    const int tid = threadIdx.x, lane = tid & 63, wave = tid >> 6;
    const int row0 = blockIdx.x * 32;
    const int jspk = row0 >> 6;
    frag_cd acc[2][4];
    #pragma unroll
    for (int rr = 0; rr < 2; ++rr)
        #pragma unroll
        for (int cc = 0; cc < 4; ++cc) acc[rr][cc] = (frag_cd){0.f, 0.f, 0.f, 0.f};
    const int ar = tid >> 3, ak = (tid & 7) << 2;
    const float* aptr = emb + (size_t)(row0 + ar) * DDIM + ak;
    float qacc = 0.f;
    const int bi = tid >> 2, bk = (tid & 3) << 3;
    const int am = lane & 15, kq = (lane >> 4) << 3;
    for (int k0 = 0; k0 < DDIM; k0 += 32) {
        __syncthreads();
        float4 av = *(const float4*)(aptr + k0);
        qacc += av.x * av.x + av.y * av.y + av.z * av.z + av.w * av.w;
        *(uint2*)&Asm[ar][ak] = make_uint2(pack2(av.x, av.y), pack2(av.z, av.w));
        #pragma unroll
        for (int p = 0; p < 4; ++p) {
            int brow = p * 64 + bi;
            *(uint4*)&Bsm[brow][bk] = *(const uint4*)(cbf + (size_t)brow * DDIM + k0 + bk);
        }
        __syncthreads();
        frag_ab afr[2], bfr[4];
        #pragma unroll
        for (int rr = 0; rr < 2; ++rr) afr[rr] = *(const frag_ab*)&Asm[rr * 16 + am][kq];
        #pragma unroll
        for (int cc = 0; cc < 4; ++cc) bfr[cc] = *(const frag_ab*)&Bsm[wave * 64 + cc * 16 + am][kq];
        #pragma unroll
        for (int rr = 0; rr < 2; ++rr)
            #pragma unroll
            for (int cc = 0; cc < 4; ++cc)
                acc[rr][cc] = __builtin_amdgcn_mfma_f32_16x16x32_bf16(afr[rr], bfr[cc], acc[rr][cc], 0, 0, 0);
    }
    qpart[ar][tid & 7] = qacc;
    __syncthreads();
    if (tid < 32) {
        float s = 0.f;
        #pragma unroll
        for (int u = 0; u < 8; ++u) s += qpart[tid][u];
        qfin[tid] = s;
    }
    __syncthreads();
    const float wv = wp[0], bv = bp[0];
    const float ns2 = normS2g[jspk], ns = normSg[jspk];
    #pragma unroll
    for (int rr = 0; rr < 2; ++rr) {
        int rbase = rr * 16 + ((lane >> 4) << 2);
        #pragma unroll
        for (int cc = 0; cc < 4; ++cc) {
            int col = wave * 64 + cc * 16 + (lane & 15);
            frag_cd v = acc[rr][cc];
            #pragma unroll
            for (int r2 = 0; r2 < 4; ++r2) {
                int lrow = rbase + r2;
                float val = v[r2];
                if (col == jspk) {
                    float q = qfin[lrow];
                    float rd = val * ns;
                    float den2 = ns2 - 2.f * rd + q;
                    val = (rd - q) * rsqrtf(fmaxf(den2, 1e-12f));
                }
                out[(size_t)(row0 + lrow) * NSPK + col] = wv * val + bv;
            }
        }
    }
}

extern "C" void kernel_launch(void* const* d_in, const int* in_sizes, int n_in,
                              void* d_out, int out_size, void* d_ws, size_t ws_size,
                              hipStream_t stream) {
    const float* emb = (const float*)d_in[0];
    const float* w   = (const float*)d_in[1];
    const float* b   = (const float*)d_in[2];
    float* out = (float*)d_out;

    const size_t sz_Sp  = (size_t)4 * NSPK * DDIM * 4;
    const size_t sz_ebf = (size_t)NROW * DDIM * 2;
    const size_t sz_cbf = (size_t)NSPK * DDIM * 2;
    const size_t sz_qg  = (size_t)NROW * 4;
    const size_t need = sz_Sp + sz_ebf + sz_cbf + sz_qg + 2 * NSPK * 4;

    if (ws_size >= need) {
        char* p = (char*)d_ws;
        float* Sp = (float*)p;              p += sz_Sp;
        unsigned short* ebf = (unsigned short*)p; p += sz_ebf;
        unsigned short* cbf = (unsigned short*)p; p += sz_cbf;
        float* qg = (float*)p;              p += sz_qg;
        float* n2 = (float*)p;              p += NSPK * 4;
        float* n1 = n2 + NSPK;
        k_prep<<<dim3(NSPK, 4), 256, 0, stream>>>(emb, Sp, ebf, qg);
        k_center<4><<<NSPK, 256, 0, stream>>>(Sp, cbf, n2, n1);
        k_gemm3<<<dim3(NROW / RT, NSPK / CT), 256, 0, stream>>>(ebf, cbf, qg, n2, n1, w, b, out);
    } else {
        float* Sp = (float*)d_ws;
        unsigned short* cbf = (unsigned short*)(Sp + 2 * NSPK * DDIM);
        float* n2 = (float*)(cbf + NSPK * DDIM);
        float* n1 = n2 + NSPK;
        k_sums<<<dim3(NSPK, 2), 256, 0, stream>>>(emb, Sp);
        k_center<2><<<NSPK, 256, 0, stream>>>(Sp, cbf, n2, n1);
        k_gemm_old<<<NROW / 32, 256, 0, stream>>>(emb, cbf, n2, n1, w, b, out);
    }
}

// Round 4
// 126.187 us; speedup vs baseline: 1.3596x; 1.3596x over previous
//
#include <hip/hip_runtime.h>

#define NSPK 256
#define MUTT 64
#define DDIM 1024
#define NROW (NSPK * MUTT)   // 16384

using frag_ab = __attribute__((ext_vector_type(8))) short;   // 8 bf16 (4 VGPRs)
using frag_cd = __attribute__((ext_vector_type(4))) float;   // 4 fp32 acc

static __device__ __forceinline__ unsigned short f32_to_bf16(float f) {
    unsigned int u = __float_as_uint(f);
    return (unsigned short)((u + 0x7FFFu + ((u >> 16) & 1u)) >> 16);   // RNE
}
static __device__ __forceinline__ unsigned int pack2(float a, float b) {
    return (unsigned)f32_to_bf16(a) | ((unsigned)f32_to_bf16(b) << 16);
}
static __device__ __forceinline__ void gload16(const void* g, void* l) {
    __builtin_amdgcn_global_load_lds(
        (const __attribute__((address_space(1))) unsigned int*)g,
        (__attribute__((address_space(3))) unsigned int*)l, 16, 0, 0);
}

// ======================= FAST PATH =======================

// k_prep (v1, reverted from regressed v2): grid (NSPK, 4), 256 thr, 16 rows/block.
// Thread t owns 4 columns across all 16 rows -> 16 independent float4 loads.
__global__ void __launch_bounds__(256) k_prep(const float* __restrict__ emb,
                                              float* __restrict__ Sp,
                                              unsigned short* __restrict__ ebf,
                                              float* __restrict__ qg) {
    const int j = blockIdx.x;
    const int h = blockIdx.y;
    const int t = threadIdx.x;
    const int lane = t & 63, wave = t >> 6;
    const size_t rowbase = (size_t)j * MUTT + (size_t)h * 16;
    const float* src = emb + rowbase * DDIM + (size_t)t * 4;
    unsigned short* edst = ebf + rowbase * DDIM + (size_t)t * 4;
    __shared__ float qws[16][4];
    float4 s = make_float4(0.f, 0.f, 0.f, 0.f);
    #pragma unroll
    for (int m = 0; m < 16; ++m) {
        float4 v = *(const float4*)(src + (size_t)m * DDIM);
        s.x += v.x; s.y += v.y; s.z += v.z; s.w += v.w;
        float qp = v.x * v.x + v.y * v.y + v.z * v.z + v.w * v.w;
        #pragma unroll
        for (int off = 32; off > 0; off >>= 1) qp += __shfl_down(qp, off, 64);
        if (lane == 0) qws[m][wave] = qp;
        *(uint2*)(edst + (size_t)m * DDIM) = make_uint2(pack2(v.x, v.y), pack2(v.z, v.w));
    }
    __syncthreads();
    if (t < 16) qg[rowbase + t] = qws[t][0] + qws[t][1] + qws[t][2] + qws[t][3];
    *(float4*)(Sp + ((size_t)h * NSPK + j) * DDIM + (size_t)t * 4) = s;
}

template <int P>
__global__ void k_center(const float* __restrict__ Sp, unsigned short* __restrict__ cbf,
                         float* __restrict__ normS2g, float* __restrict__ normSg) {
    const int j = blockIdx.x;
    const int t = threadIdx.x;
    float4 v = make_float4(0.f, 0.f, 0.f, 0.f);
    #pragma unroll
    for (int p = 0; p < P; ++p) {
        float4 a = *(const float4*)(Sp + ((size_t)p * NSPK + j) * DDIM + (size_t)t * 4);
        v.x += a.x; v.y += a.y; v.z += a.z; v.w += a.w;
    }
    float sq = v.x * v.x + v.y * v.y + v.z * v.z + v.w * v.w;
    #pragma unroll
    for (int off = 32; off > 0; off >>= 1) sq += __shfl_down(sq, off, 64);
    __shared__ float ws[4];
    __shared__ float sc_sh;
    const int lane = t & 63, wave = t >> 6;
    if (lane == 0) ws[wave] = sq;
    __syncthreads();
    if (t == 0) {
        float tot = ws[0] + ws[1] + ws[2] + ws[3];
        normS2g[j] = tot;
        normSg[j]  = sqrtf(tot);
        float msq = tot * (1.0f / 4096.0f);
        sc_sh = rsqrtf(fmaxf(msq, 1e-12f)) * (1.0f / 64.0f);
    }
    __syncthreads();
    const float sc = sc_sh;
    *(uint2*)(cbf + (size_t)j * DDIM + (size_t)t * 4) =
        make_uint2(pack2(v.x * sc, v.y * sc), pack2(v.z * sc, v.w * sc));
}

// k_gemm4: 64x64 tile, BK=64, grid (256,4)=1024 blocks (~5 blocks/CU),
// double-buffered LDS (32 KB) staged via global_load_lds width=16 (unsinkable),
// single barrier per iter. XOR swizzle (chunk ^= row&7) -> conflict-free b128 reads.
#define BK 64
__global__ void __launch_bounds__(256, 5)
k_gemm4(const unsigned short* __restrict__ ebf, const unsigned short* __restrict__ cbf,
        const float* __restrict__ qg, const float* __restrict__ n2g,
        const float* __restrict__ n1g,
        const float* __restrict__ wp, const float* __restrict__ bp,
        float* __restrict__ out) {
    __shared__ unsigned short lds[2 * 8192];   // 2 buffers x (A 4096 + B 4096 shorts)

    const int tid = threadIdx.x, lane = tid & 63, wave = tid >> 6;
    const int rt = blockIdx.x;            // speaker / 64-row tile
    const int ct = blockIdx.y;            // 64-col tile
    const int row0 = rt * 64;
    const int c0 = ct * 64;
    const int jspk = rt;

    // staging offsets: chunk = 16 B; row has 8 chunks (BK=64 bf16 = 128 B).
    // LDS chunk (row, sw) holds G[row][sw ^ (row&7)].
    int aoff[2], boff[2];
    #pragma unroll
    for (int i = 0; i < 2; ++i) {
        int c = i * 256 + tid, row = c >> 3, sw = c & 7;
        int off = row * (DDIM * 2) + ((sw ^ (row & 7)) << 4);
        aoff[i] = off; boff[i] = off;     // same shape for A and B (64 rows)
    }
    const int stbase = wave * 512;        // shorts; wave-uniform LDS base (+ i*2048)
    const char* agbase = (const char*)(ebf + (size_t)row0 * DDIM);
    const char* bgbase = (const char*)(cbf + (size_t)c0 * DDIM);

    const int quad = lane >> 4;
    const int m16 = lane & 15;
    const int wrow = wave >> 1, wcol = wave & 1;   // 2x2 wave grid, 32x32 each
    int arow[2], brow[2];
    #pragma unroll
    for (int rr = 0; rr < 2; ++rr) arow[rr] = wrow * 32 + rr * 16 + m16;
    #pragma unroll
    for (int cc = 0; cc < 2; ++cc) brow[cc] = wcol * 32 + cc * 16 + m16;

    frag_cd acc[2][2];
    #pragma unroll
    for (int rr = 0; rr < 2; ++rr)
        #pragma unroll
        for (int cc = 0; cc < 2; ++cc) acc[rr][cc] = (frag_cd){0.f, 0.f, 0.f, 0.f};

    // prologue: stage tile 0 into buffer 0
    #pragma unroll
    for (int i = 0; i < 2; ++i) {
        gload16(agbase + aoff[i], &lds[i * 2048 + stbase]);
        gload16(bgbase + boff[i], &lds[4096 + i * 2048 + stbase]);
    }
    __syncthreads();

    const int NIT = DDIM / BK;   // 16
    for (int it = 0; it < NIT; ++it) {
        const int cur = it & 1;
        if (it + 1 < NIT) {       // async DMA prefetch into other buffer
            const char* ag = agbase + (size_t)(it + 1) * BK * 2;
            const char* bg = bgbase + (size_t)(it + 1) * BK * 2;
            unsigned short* Ln = &lds[(cur ^ 1) * 8192];
            #pragma unroll
            for (int i = 0; i < 2; ++i) {
                gload16(ag + aoff[i], Ln + i * 2048 + stbase);
                gload16(bg + boff[i], Ln + 4096 + i * 2048 + stbase);
            }
        }
        const unsigned short* L = &lds[cur * 8192];
        #pragma unroll
        for (int s = 0; s < 2; ++s) {
            const int kc = (s << 1) + (quad >> 1);     // unused placeholder removed below
        }
        #pragma unroll
        for (int s = 0; s < 2; ++s) {
            frag_ab af[2], bf[2];
            const int kc = (s << 2) + quad;            // chunk-in-row 0..7
            #pragma unroll
            for (int rr = 0; rr < 2; ++rr) {
                int addr = arow[rr] * 128 + ((kc ^ (arow[rr] & 7)) << 4);
                af[rr] = *(const frag_ab*)&L[addr >> 1];
            }
            #pragma unroll
            for (int cc = 0; cc < 2; ++cc) {
                int addr = 8192 + brow[cc] * 128 + ((kc ^ (brow[cc] & 7)) << 4);
                bf[cc] = *(const frag_ab*)&L[addr >> 1];
            }
            #pragma unroll
            for (int rr = 0; rr < 2; ++rr)
                #pragma unroll
                for (int cc = 0; cc < 2; ++cc)
                    acc[rr][cc] = __builtin_amdgcn_mfma_f32_16x16x32_bf16(
                        af[rr], bf[cc], acc[rr][cc], 0, 0, 0);
        }
        __syncthreads();   // drains prefetch vmcnt + joins waves before buffer swap
    }

    const float wv = wp[0], bv = bp[0];
    const float ns2 = n2g[jspk], ns = n1g[jspk];
    #pragma unroll
    for (int rr = 0; rr < 2; ++rr) {
        int rbase = wrow * 32 + rr * 16 + (quad << 2);
        #pragma unroll
        for (int cc = 0; cc < 2; ++cc) {
            int col = c0 + wcol * 32 + cc * 16 + m16;
            frag_cd v = acc[rr][cc];
            #pragma unroll
            for (int r2 = 0; r2 < 4; ++r2) {
                int grow = row0 + rbase + r2;
                float val = v[r2];
                if (col == jspk) {
                    float q = qg[grow];
                    float rd = val * ns;
                    float den2 = ns2 - 2.f * rd + q;
                    val = (rd - q) * rsqrtf(fmaxf(den2, 1e-12f));
                }
                out[(size_t)grow * NSPK + col] = wv * val + bv;
            }
        }
    }
}

// ======================= FALLBACK (small ws) =======================

__global__ void k_sums(const float* __restrict__ emb, float* __restrict__ Sp) {
    const int j = blockIdx.x;
    const int h = blockIdx.y;
    const int c = threadIdx.x;
    const float* base = emb + ((size_t)j * MUTT + (size_t)h * 32) * DDIM + (size_t)c * 4;
    float4 acc = make_float4(0.f, 0.f, 0.f, 0.f);
    #pragma unroll 8
    for (int m = 0; m < 32; ++m) {
        float4 v = *(const float4*)(base + (size_t)m * DDIM);
        acc.x += v.x; acc.y += v.y; acc.z += v.z; acc.w += v.w;
    }
    *(float4*)(Sp + ((size_t)h * NSPK + j) * DDIM + (size_t)c * 4) = acc;
}

__global__ void __launch_bounds__(256)
k_gemm_old(const float* __restrict__ emb, const unsigned short* __restrict__ cbf,
           const float* __restrict__ normS2g, const float* __restrict__ normSg,
           const float* __restrict__ wp, const float* __restrict__ bp,
           float* __restrict__ out) {
    __shared__ unsigned short Asm[32][32];
    __shared__ unsigned short Bsm[256][32];
    __shared__ float qpart[32][8];
    __shared__ float qfin[32];
    const int tid = threadIdx.x, lane = tid & 63, wave = tid >> 6;
    const int row0 = blockIdx.x * 32;
    const int jspk = row0 >> 6;
    frag_cd acc[2][4];
    #pragma unroll
    for (int rr = 0; rr < 2; ++rr)
        #pragma unroll
        for (int cc = 0; cc < 4; ++cc) acc[rr][cc] = (frag_cd){0.f, 0.f, 0.f, 0.f};
    const int ar = tid >> 3, ak = (tid & 7) << 2;
    const float* aptr = emb + (size_t)(row0 + ar) * DDIM + ak;
    float qacc = 0.f;
    const int bi = tid >> 2, bk = (tid & 3) << 3;
    const int am = lane & 15, kq = (lane >> 4) << 3;
    for (int k0 = 0; k0 < DDIM; k0 += 32) {
        __syncthreads();
        float4 av = *(const float4*)(aptr + k0);
        qacc += av.x * av.x + av.y * av.y + av.z * av.z + av.w * av.w;
        *(uint2*)&Asm[ar][ak] = make_uint2(pack2(av.x, av.y), pack2(av.z, av.w));
        #pragma unroll
        for (int p = 0; p < 4; ++p) {
            int brow = p * 64 + bi;
            *(uint4*)&Bsm[brow][bk] = *(const uint4*)(cbf + (size_t)brow * DDIM + k0 + bk);
        }
        __syncthreads();
        frag_ab afr[2], bfr[4];
        #pragma unroll
        for (int rr = 0; rr < 2; ++rr) afr[rr] = *(const frag_ab*)&Asm[rr * 16 + am][kq];
        #pragma unroll
        for (int cc = 0; cc < 4; ++cc) bfr[cc] = *(const frag_ab*)&Bsm[wave * 64 + cc * 16 + am][kq];
        #pragma unroll
        for (int rr = 0; rr < 2; ++rr)
            #pragma unroll
            for (int cc = 0; cc < 4; ++cc)
                acc[rr][cc] = __builtin_amdgcn_mfma_f32_16x16x32_bf16(afr[rr], bfr[cc], acc[rr][cc], 0, 0, 0);
    }
    qpart[ar][tid & 7] = qacc;
    __syncthreads();
    if (tid < 32) {
        float s = 0.f;
        #pragma unroll
        for (int u = 0; u < 8; ++u) s += qpart[tid][u];
        qfin[tid] = s;
    }
    __syncthreads();
    const float wv = wp[0], bv = bp[0];
    const float ns2 = normS2g[jspk], ns = normSg[jspk];
    #pragma unroll
    for (int rr = 0; rr < 2; ++rr) {
        int rbase = rr * 16 + ((lane >> 4) << 2);
        #pragma unroll
        for (int cc = 0; cc < 4; ++cc) {
            int col = wave * 64 + cc * 16 + (lane & 15);
            frag_cd v = acc[rr][cc];
            #pragma unroll
            for (int r2 = 0; r2 < 4; ++r2) {
                int lrow = rbase + r2;
                float val = v[r2];
                if (col == jspk) {
                    float q = qfin[lrow];
                    float rd = val * ns;
                    float den2 = ns2 - 2.f * rd + q;
                    val = (rd - q) * rsqrtf(fmaxf(den2, 1e-12f));
                }
                out[(size_t)(row0 + lrow) * NSPK + col] = wv * val + bv;
            }
        }
    }
}

extern "C" void kernel_launch(void* const* d_in, const int* in_sizes, int n_in,
                              void* d_out, int out_size, void* d_ws, size_t ws_size,
                              hipStream_t stream) {
    const float* emb = (const float*)d_in[0];
    const float* w   = (const float*)d_in[1];
    const float* b   = (const float*)d_in[2];
    float* out = (float*)d_out;

    const size_t sz_Sp  = (size_t)4 * NSPK * DDIM * 4;
    const size_t sz_ebf = (size_t)NROW * DDIM * 2;
    const size_t sz_cbf = (size_t)NSPK * DDIM * 2;
    const size_t sz_qg  = (size_t)NROW * 4;
    const size_t need = sz_Sp + sz_ebf + sz_cbf + sz_qg + 2 * NSPK * 4;

    if (ws_size >= need) {
        char* p = (char*)d_ws;
        float* Sp = (float*)p;              p += sz_Sp;
        unsigned short* ebf = (unsigned short*)p; p += sz_ebf;
        unsigned short* cbf = (unsigned short*)p; p += sz_cbf;
        float* qg = (float*)p;              p += sz_qg;
        float* n2 = (float*)p;              p += NSPK * 4;
        float* n1 = n2 + NSPK;
        k_prep<<<dim3(NSPK, 4), 256, 0, stream>>>(emb, Sp, ebf, qg);
        k_center<4><<<NSPK, 256, 0, stream>>>(Sp, cbf, n2, n1);
        k_gemm4<<<dim3(NSPK, 4), 256, 0, stream>>>(ebf, cbf, qg, n2, n1, w, b, out);
    } else {
        float* Sp = (float*)d_ws;
        unsigned short* cbf = (unsigned short*)(Sp + 2 * NSPK * DDIM);
        float* n2 = (float*)(cbf + NSPK * DDIM);
        float* n1 = n2 + NSPK;
        k_sums<<<dim3(NSPK, 2), 256, 0, stream>>>(emb, Sp);
        k_center<2><<<NSPK, 256, 0, stream>>>(Sp, cbf, n2, n1);
        k_gemm_old<<<NROW / 32, 256, 0, stream>>>(emb, cbf, n2, n1, w, b, out);
    }
}